// Round 1
// 227.255 us; speedup vs baseline: 1.0377x; 1.0377x over previous
//
#include <hip/hip_runtime.h>
#include <hip/hip_fp16.h>

// GCN encoder: out = A' relu(A' (x W1) + b1) W2 + b2, A' = D^-1/2 (A+I) D^-1/2
// Round 8: k_count/k_scatter were latency-bound at 3.6% occupancy (GC=128 blocks
// on 256 CUs, 1 block/CU on half the chip, 49 dependent iterations/thread).
// (a) GC 128->512: 2 blocks/CU everywhere, 4x waves, 12 iterations/thread.
// (b) hist transposed to [chunk][bucket]: k_count writes + k_scatter reads fully
//     coalesced (old layout would have been 51MB of strided partial lines at GC=512).
// (c) new k_scan_chunks: 16 buckets x GC chunks staged in 32KB LDS (coalesced),
//     Hillis-Steele scan over chunks; k_addback folded into k_scatter.
// (d) hist overlays the csr region (dead until k_bsort writes csr) — ws stays ~20MB.
// Algebra: g = h*dinv  =>  p[d] = dinv[d] * (g[d] + sum_{s->d} g[s]).

#define NN 100000
#define NE 1600000
#define FI 128
#define FH 16
#define CB 64                  // nodes per bucket
#define NB 1563                // ceil(NN/64); NB*64 = 100032
#define GC 512                 // edge chunks
#define CHUNK 3125             // NE/GC exactly
#define SCB 16                 // buckets per scan block

__device__ __forceinline__ float fc(const float4& v, int i) {
    return i == 0 ? v.x : i == 1 ? v.y : i == 2 ? v.z : v.w;
}

// ---------- CSR build ----------
// hist layout: hist[c * NB + b]  (chunk-major -> coalesced in count/scatter)
__global__ __launch_bounds__(256) void k_count(const int* __restrict__ dst,
                                               int* __restrict__ hist) {
    __shared__ int h[NB];
    for (int i = threadIdx.x; i < NB; i += 256) h[i] = 0;
    __syncthreads();
    int base = blockIdx.x * CHUNK;
    for (int i = base + threadIdx.x; i < base + CHUNK; i += 256)
        atomicAdd(&h[dst[i] >> 6], 1);
    __syncthreads();
    for (int b = threadIdx.x; b < NB; b += 256)
        hist[blockIdx.x * NB + b] = h[b];
}

// per-bucket exclusive scan over chunks; 16 buckets/block, coalesced loads.
__global__ __launch_bounds__(256) void k_scan_chunks(int* __restrict__ hist,
                                                     int* __restrict__ totals) {
    __shared__ int s[GC * SCB];                       // 32 KB
    int b0 = blockIdx.x * SCB;
    int o[GC * SCB / 256];
    #pragma unroll
    for (int r = 0; r < GC * SCB / 256; ++r) {
        int idx = r * 256 + threadIdx.x;
        int c = idx >> 4, bl = idx & (SCB - 1), b = b0 + bl;
        int v = (b < NB) ? hist[c * NB + b] : 0;
        s[idx] = v;
        o[r] = v;
    }
    __syncthreads();
    for (int off = 1; off < GC; off <<= 1) {
        int t[GC * SCB / 256];
        #pragma unroll
        for (int r = 0; r < GC * SCB / 256; ++r) {
            int idx = r * 256 + threadIdx.x;
            int c = idx >> 4;
            t[r] = (c >= off) ? s[idx - off * SCB] : 0;
        }
        __syncthreads();
        #pragma unroll
        for (int r = 0; r < GC * SCB / 256; ++r) {
            int idx = r * 256 + threadIdx.x;
            s[idx] += t[r];
        }
        __syncthreads();
    }
    #pragma unroll
    for (int r = 0; r < GC * SCB / 256; ++r) {
        int idx = r * 256 + threadIdx.x;
        int c = idx >> 4, bl = idx & (SCB - 1), b = b0 + bl;
        if (b < NB) {
            hist[c * NB + b] = s[idx] - o[r];          // exclusive within bucket
            if (c == GC - 1) totals[b] = s[idx];       // bucket total
        }
    }
}

__global__ __launch_bounds__(1024) void k_scan_buckets(const int* __restrict__ totals,
                                                       int* __restrict__ bucketStart,
                                                       int* __restrict__ rowStart) {
    __shared__ int s[1024];
    int tid = threadIdx.x;
    int i0 = 2 * tid, i1 = i0 + 1;
    int a = (i0 < NB) ? totals[i0] : 0;
    int b = (i1 < NB) ? totals[i1] : 0;
    s[tid] = a + b;
    __syncthreads();
    #pragma unroll
    for (int off = 1; off < 1024; off <<= 1) {
        int t = (tid >= off) ? s[tid - off] : 0;
        __syncthreads();
        s[tid] += t;
        __syncthreads();
    }
    int excl = s[tid] - (a + b);
    if (i0 < NB) bucketStart[i0] = excl;
    if (i1 < NB) bucketStart[i1] = excl + a;
    if (tid == 0) { bucketStart[NB] = NE; rowStart[NN] = NE; }
}

__global__ __launch_bounds__(256) void k_scatter(const int* __restrict__ src,
                                                 const int* __restrict__ dst,
                                                 const int* __restrict__ hist,
                                                 const int* __restrict__ bucketStart,
                                                 int* __restrict__ packed) {
    __shared__ int cur[NB];
    for (int b = threadIdx.x; b < NB; b += 256)
        cur[b] = hist[blockIdx.x * NB + b] + bucketStart[b];   // addback folded in
    __syncthreads();
    int base = blockIdx.x * CHUNK;
    for (int i = base + threadIdx.x; i < base + CHUNK; i += 256) {
        int d = dst[i];
        int pos = atomicAdd(&cur[d >> 6], 1);
        packed[pos] = src[i] | ((d & 63) << 17);   // src < 2^17, local node in [0,64)
    }
}

// per-bucket sort -> exact CSR + rowStart + dinv (int LDS atomics only)
__global__ __launch_bounds__(256) void k_bsort(const int* __restrict__ packed,
                                               const int* __restrict__ bucketStart,
                                               int* __restrict__ csr,
                                               int* __restrict__ rowStart,
                                               float* __restrict__ dinv) {
    __shared__ int cnt[CB];
    __shared__ int rs[CB];
    __shared__ int cur[CB];
    if (threadIdx.x < CB) cnt[threadIdx.x] = 0;
    __syncthreads();
    int s0 = bucketStart[blockIdx.x], s1 = bucketStart[blockIdx.x + 1];
    for (int i = s0 + threadIdx.x; i < s1; i += 256)
        atomicAdd(&cnt[(packed[i] >> 17) & 63], 1);
    __syncthreads();
    if (threadIdx.x < CB) rs[threadIdx.x] = cnt[threadIdx.x];
    __syncthreads();
    #pragma unroll
    for (int off = 1; off < CB; off <<= 1) {
        int t = 0;
        if (threadIdx.x < CB && threadIdx.x >= off) t = rs[threadIdx.x - off];
        __syncthreads();
        if (threadIdx.x < CB) rs[threadIdx.x] += t;
        __syncthreads();
    }
    if (threadIdx.x < CB) {
        int start = s0 + rs[threadIdx.x] - cnt[threadIdx.x];   // exclusive
        cur[threadIdx.x] = start;
        int node = blockIdx.x * CB + threadIdx.x;
        if (node < NN) {
            rowStart[node] = start;
            dinv[node] = rsqrtf((float)(cnt[threadIdx.x] + 1));
        }
    }
    __syncthreads();
    for (int i = s0 + threadIdx.x; i < s1; i += 256) {
        int pk = packed[i];
        int pos = atomicAdd(&cur[(pk >> 17) & 63], 1);
        csr[pos] = pk & 131071;
    }
}

// ---------- dense ops ----------
// g1 = f16((x @ W1) * dinv); 256 nodes/block, thread = 4 nodes x 4 feats
__global__ __launch_bounds__(256) void k_gemm1(const float* __restrict__ x,
                                               const float* __restrict__ W1,
                                               const float* __restrict__ dinv,
                                               __half2* __restrict__ g1) {
    __shared__ __align__(16) float w[FI * FH];
    float4* w4s = (float4*)w;
    w4s[threadIdx.x] = ((const float4*)W1)[threadIdx.x];
    w4s[threadIdx.x + 256] = ((const float4*)W1)[threadIdx.x + 256];
    __syncthreads();
    int fg = threadIdx.x & 3;          // feature quad: f = fg*4..fg*4+3
    int ng = threadIdx.x >> 2;         // node group
    int r0 = blockIdx.x * 256 + ng * 4;
    const float4* x4 = (const float4*)x;
    int rr[4]; bool val[4];
    #pragma unroll
    for (int i = 0; i < 4; ++i) {
        val[i] = (r0 + i < NN);
        rr[i] = val[i] ? r0 + i : NN - 1;
    }
    float acc[4][4];
    #pragma unroll
    for (int i = 0; i < 4; ++i)
        #pragma unroll
        for (int j = 0; j < 4; ++j) acc[i][j] = 0.f;
    #pragma unroll 2
    for (int k4 = 0; k4 < 32; ++k4) {
        float4 xv[4];
        #pragma unroll
        for (int i = 0; i < 4; ++i) xv[i] = x4[rr[i] * 32 + k4];
        #pragma unroll
        for (int kk = 0; kk < 4; ++kk) {
            float4 wv = w4s[(k4 * 4 + kk) * 4 + fg];
            #pragma unroll
            for (int i = 0; i < 4; ++i) {
                float xk = fc(xv[i], kk);
                acc[i][0] += xk * wv.x; acc[i][1] += xk * wv.y;
                acc[i][2] += xk * wv.z; acc[i][3] += xk * wv.w;
            }
        }
    }
    #pragma unroll
    for (int i = 0; i < 4; ++i) if (val[i]) {
        float dv = dinv[rr[i]];
        g1[rr[i] * 8 + fg * 2]     = __floats2half2_rn(acc[i][0] * dv, acc[i][1] * dv);
        g1[rr[i] * 8 + fg * 2 + 1] = __floats2half2_rn(acc[i][2] * dv, acc[i][3] * dv);
    }
}

// gather agg: 8 threads/node, f32 register accumulation, zero atomics.
// RELU=true:  g2 = f16(relu(dinv*(g_d + sum) + b1) * dinv)
// RELU=false: p2 = dinv*(g_d + sum)   (f32)
template<bool RELU>
__global__ __launch_bounds__(256) void k_agg(const int* __restrict__ csr,
                                             const int* __restrict__ rowStart,
                                             const __half2* __restrict__ gin,
                                             const float* __restrict__ dinv,
                                             const float* __restrict__ b1,
                                             __half2* __restrict__ gh_out,
                                             float2* __restrict__ p2f) {
    int gid = blockIdx.x * 256 + threadIdx.x;
    int node = gid >> 3, c = gid & 7;
    if (node >= NN) return;
    int s0 = rowStart[node], s1 = rowStart[node + 1];
    float2 acc = __half22float2(gin[node * 8 + c]);   // self-loop term
    int e = s0;
    for (; e + 3 < s1; e += 4) {
        int i0 = csr[e], i1 = csr[e + 1], i2 = csr[e + 2], i3 = csr[e + 3];
        float2 f0 = __half22float2(gin[i0 * 8 + c]);
        float2 f1 = __half22float2(gin[i1 * 8 + c]);
        float2 f2 = __half22float2(gin[i2 * 8 + c]);
        float2 f3 = __half22float2(gin[i3 * 8 + c]);
        acc.x += (f0.x + f1.x) + (f2.x + f3.x);
        acc.y += (f0.y + f1.y) + (f2.y + f3.y);
    }
    for (; e < s1; ++e) {
        float2 f = __half22float2(gin[csr[e] * 8 + c]);
        acc.x += f.x; acc.y += f.y;
    }
    float dv = dinv[node];
    if (RELU) {
        float2 bb = *(const float2*)(b1 + 2 * c);
        float vx = fmaxf(dv * acc.x + bb.x, 0.f) * dv;
        float vy = fmaxf(dv * acc.y + bb.y, 0.f) * dv;
        gh_out[node * 8 + c] = __floats2half2_rn(vx, vy);
    } else {
        p2f[node * 8 + c] = make_float2(dv * acc.x, dv * acc.y);
    }
}

// out = p2 @ W2 + b2; 32 nodes/block, thread = 4 nodes x 4 feats
__global__ __launch_bounds__(256) void k_gemm2(const float* __restrict__ p2s,
                                               const float* __restrict__ W2,
                                               const float* __restrict__ b2,
                                               float* __restrict__ out) {
    __shared__ __align__(16) float w[FH * FI];
    __shared__ __align__(16) float pst[FH][32];   // transposed p2 tile
    float4* w4s = (float4*)w;
    w4s[threadIdx.x] = ((const float4*)W2)[threadIdx.x];
    w4s[threadIdx.x + 256] = ((const float4*)W2)[threadIdx.x + 256];
    int base = blockIdx.x * 32;
    {
        int n = threadIdx.x >> 4, k = threadIdx.x & 15;
        int gn = base + n;
        pst[k][n] = (gn < NN) ? p2s[gn * 16 + k] : 0.f;
        n += 16; gn = base + n;
        pst[k][n] = (gn < NN) ? p2s[gn * 16 + k] : 0.f;
    }
    __syncthreads();
    int fg = threadIdx.x & 31;    // feature quad: f = fg*4..fg*4+3
    int ng = threadIdx.x >> 5;    // node group: n = ng*4..ng*4+3
    float4 bb = ((const float4*)b2)[fg];
    float acc[4][4];
    #pragma unroll
    for (int i = 0; i < 4; ++i) {
        acc[i][0] = bb.x; acc[i][1] = bb.y; acc[i][2] = bb.z; acc[i][3] = bb.w;
    }
    #pragma unroll
    for (int k = 0; k < FH; ++k) {
        float4 xk = *(float4*)&pst[k][ng * 4];
        float4 wv = w4s[k * 32 + fg];
        #pragma unroll
        for (int i = 0; i < 4; ++i) {
            float xv = fc(xk, i);
            acc[i][0] += xv * wv.x; acc[i][1] += xv * wv.y;
            acc[i][2] += xv * wv.z; acc[i][3] += xv * wv.w;
        }
    }
    #pragma unroll
    for (int i = 0; i < 4; ++i) {
        int gn = base + ng * 4 + i;
        if (gn < NN)
            ((float4*)out)[gn * 32 + fg] =
                make_float4(acc[i][0], acc[i][1], acc[i][2], acc[i][3]);
    }
}

extern "C" void kernel_launch(void* const* d_in, const int* in_sizes, int n_in,
                              void* d_out, int out_size, void* d_ws, size_t ws_size,
                              hipStream_t stream) {
    const float* x  = (const float*)d_in[0];
    const int*   ei = (const int*)d_in[1];
    const float* W1 = (const float*)d_in[2];
    const float* b1 = (const float*)d_in[3];
    const float* W2 = (const float*)d_in[4];
    const float* b2 = (const float*)d_in[5];
    float* out = (float*)d_out;

    const int* src = ei;
    const int* dst = ei + NE;

    // workspace layout (~20.0 MB total, 4-B units)
    int*   totals      = (int*)d_ws;                  // [NB]
    int*   bucketStart = totals + NB;                 // [NB+1]
    int*   rowStart    = bucketStart + NB + 1;        // [NN+1]
    float* dinv        = (float*)(rowStart + NN + 1); // [NN]
    int*   csr         = (int*)(dinv + NN);           // [NE]
    int*   hist        = csr;                         // [GC*NB]=800256 <= NE, dead before k_bsort
    int*   packed      = csr + NE;                    // [NE] -> reused as g1,g2
    __half2* g1        = (__half2*)packed;            // [NN*8] (800k ints)
    __half2* g2        = g1 + NN * 8;                 // [NN*8] (800k ints)
    float2*  p2f       = (float2*)(packed + NE);      // [NN*8] (1.6M ints)

    k_count       <<<GC, 256, 0, stream>>>(dst, hist);
    k_scan_chunks <<<(NB + SCB - 1) / SCB, 256, 0, stream>>>(hist, totals);
    k_scan_buckets<<<1, 1024, 0, stream>>>(totals, bucketStart, rowStart);
    k_scatter     <<<GC, 256, 0, stream>>>(src, dst, hist, bucketStart, packed);
    k_bsort       <<<NB, 256, 0, stream>>>(packed, bucketStart, csr, rowStart, dinv);

    k_gemm1       <<<(NN + 255) / 256, 256, 0, stream>>>(x, W1, dinv, g1);
    k_agg<true>   <<<(NN * 8) / 256, 256, 0, stream>>>(csr, rowStart, g1, dinv, b1, g2, (float2*)nullptr);
    k_agg<false>  <<<(NN * 8) / 256, 256, 0, stream>>>(csr, rowStart, g2, dinv, b1, (__half2*)nullptr, p2f);
    k_gemm2       <<<(NN + 31) / 32, 256, 0, stream>>>((const float*)p2f, W2, b2, out);
}